// Round 3
// baseline (25869.345 us; speedup 1.0000x reference)
//
#include <hip/hip_runtime.h>
#include <hip/hip_bf16.h>

typedef __attribute__((ext_vector_type(8))) short bf16x8;
typedef __attribute__((ext_vector_type(4))) float f32x4;

#define NB 512      // batch
#define NT 128      // timesteps
#define NC 66       // input channels
#define NH 512      // hidden
#define NW 10       // window
#define CP 96       // padded C (multiple of 32)
#define BM 32       // batch tile
#define BJ 64       // j (h-dim) tile -> 3 gate chunks of 64 cols each
#define BK 32       // K step (MFMA K=32)
#define BKP 40      // padded LDS row stride (80B = 5*16B: breaks 8-way bank aliasing)
#define NWG 256
#define NTHR 256
#define G3 1536     // 3*NH

struct Params {
  const float *x, *Wih0, *Whh0, *bih0, *bhh0, *Wih1, *Whh1, *bih1, *bhh1, *tw, *tb, *sw, *sb;
  float *out;
  unsigned *bar;                       // software grid-barrier counter (memset to 0 on stream)
  __hip_bfloat16 *Wih0h, *Wih0l;       // layer0 input weights: always pre-split (K padded to CP)
  __hip_bfloat16 *Whh0h, *Whh0l, *Wih1h, *Wih1l, *Whh1h, *Whh1l;  // only valid if PS
  float *h0, *h1, *decin, *ghh1, *tvec;
  __hip_bfloat16 *winb;                // sliding window, bf16
};

__device__ __forceinline__ float sigmoidf_(float x) { return 1.f / (1.f + __expf(-x)); }
__device__ __forceinline__ float tanhf_(float x) {
  float e = __expf(2.f * x);
  return (e - 1.f) / (e + 1.f);
}
__device__ __forceinline__ void split2(float v, __hip_bfloat16& h, __hip_bfloat16& l) {
  h = __float2bfloat16(v);
  l = __float2bfloat16(v - __bfloat162float(h));
}
__device__ __forceinline__ unsigned short bfbits(__hip_bfloat16 h) { return *(unsigned short*)&h; }
__device__ __forceinline__ void splitpack4(float4 v, ushort4& ph, ushort4& pl) {
  __hip_bfloat16 h, l;
  split2(v.x, h, l); ph.x = bfbits(h); pl.x = bfbits(l);
  split2(v.y, h, l); ph.y = bfbits(h); pl.y = bfbits(l);
  split2(v.z, h, l); ph.z = bfbits(h); pl.z = bfbits(l);
  split2(v.w, h, l); ph.w = bfbits(h); pl.w = bfbits(l);
}

// software grid barrier: monotonic counter, agent-scope atomics, tid0 spins.
// Co-residency guaranteed: NWG=256 <= 256 CUs, kernel fits >=1 block/CU.
__device__ __forceinline__ void gbar(unsigned* bar, unsigned& gen, int tid) {
  __syncthreads();
  gen += NWG;
  if (tid == 0) {
    __threadfence();   // flush my writes device-wide before announcing arrival
    __hip_atomic_fetch_add(bar, 1u, __ATOMIC_RELAXED, __HIP_MEMORY_SCOPE_AGENT);
    while (__hip_atomic_load(bar, __ATOMIC_RELAXED, __HIP_MEMORY_SCOPE_AGENT) < gen)
      __builtin_amdgcn_s_sleep(1);
    __threadfence();   // invalidate caches so subsequent reads see others' writes
  }
  __syncthreads();
}

#define AM_X 0
#define AM_DEC 1
#define AM_H 2

__device__ __forceinline__ void zacc(f32x4 acc[2][4]) {
#pragma unroll
  for (int i = 0; i < 2; ++i)
#pragma unroll
    for (int g = 0; g < 4; ++g) {
      acc[i][g][0] = 0.f; acc[i][g][1] = 0.f; acc[i][g][2] = 0.f; acc[i][g][3] = 0.f;
    }
}

// (BM x 3*BJ) tile of gates[b, g*512+j] += A[b,:] @ W[g*512+j, :]^T with split-bf16:
// acc += Ahi*Whi + Alo*Whi + Ahi*Wlo (fp32 MFMA accumulate; dropped lo*lo ~2^-18).
// PSW: weights pre-split (Wh/Wl bf16) vs on-the-fly split from fp32 Wf.
template <int G2, bool PSW>
__device__ __forceinline__ void gemm_tile(
    f32x4 acc[2][4],
    const __hip_bfloat16* __restrict__ Wh, const __hip_bfloat16* __restrict__ Wl,
    const float* __restrict__ Wf, int Kb,
    int amode, const float* __restrict__ A, int tstep,
    int b0, int j0,
    __hip_bfloat16* AsH, __hip_bfloat16* AsL,
    __hip_bfloat16* BsH, __hip_bfloat16* BsL, int tid)
{
  const int wv = tid >> 6, lane = tid & 63, quad = lane >> 4, l15 = lane & 15;
  const int ms = wv & 1, jh = wv >> 1;
  const int am = tid >> 3;          // 0..31 (A row)
  const int ak = (tid & 7) << 2;    // 0..28 (A col group of 4)
  const int nk = Kb >> 5;
  for (int kk = 0; kk < nk; ++kk) {
    const int kb = kk << 5;
    float4 av;
    if (amode == AM_X) {
      const float* xr = A + ((size_t)(b0 + am) * NT + tstep) * NC;
      const int k = kb + ak;
      av.x = (k + 0 < NC) ? xr[k + 0] : 0.f;
      av.y = (k + 1 < NC) ? xr[k + 1] : 0.f;
      av.z = (k + 2 < NC) ? xr[k + 2] : 0.f;
      av.w = (k + 3 < NC) ? xr[k + 3] : 0.f;
    } else if (amode == AM_DEC) {
      av = *(const float4*)(A + (size_t)(b0 + am) * CP + kb + ak);
    } else {
      av = *(const float4*)(A + (size_t)(b0 + am) * NH + kb + ak);
    }
    {
      ushort4 ph, pl;
      splitpack4(av, ph, pl);
      *(ushort4*)(AsH + am * BKP + ak) = ph;
      *(ushort4*)(AsL + am * BKP + ak) = pl;
    }
#pragma unroll
    for (int r = 0; r < 3; ++r) {
      const int l = tid + r * NTHR;
      const int nl = l >> 2, k8 = (l & 3) << 3;
      const int g = nl >> 6, jl = nl & 63;
      if (PSW) {
        const size_t woff = (size_t)(g * NH + j0 + jl) * Kb + kb + k8;
        *(uint4*)(BsH + nl * BKP + k8) = *(const uint4*)(Wh + woff);
        *(uint4*)(BsL + nl * BKP + k8) = *(const uint4*)(Wl + woff);
      } else {
        const float* wp = Wf + (size_t)(g * NH + j0 + jl) * Kb + kb + k8;
        float4 w0 = *(const float4*)wp;
        float4 w1 = *(const float4*)(wp + 4);
        ushort4 ph0, pl0, ph1, pl1;
        splitpack4(w0, ph0, pl0);
        splitpack4(w1, ph1, pl1);
        *(ushort4*)(BsH + nl * BKP + k8) = ph0;
        *(ushort4*)(BsH + nl * BKP + k8 + 4) = ph1;
        *(ushort4*)(BsL + nl * BKP + k8) = pl0;
        *(ushort4*)(BsL + nl * BKP + k8 + 4) = pl1;
      }
    }
    __syncthreads();
    bf16x8 ah = *(const bf16x8*)(AsH + (ms * 16 + l15) * BKP + quad * 8);
    bf16x8 al = *(const bf16x8*)(AsL + (ms * 16 + l15) * BKP + quad * 8);
#pragma unroll
    for (int jlf = 0; jlf < 2; ++jlf) {
      const int nbase = (jh * 32 + jlf * 16 + l15) * BKP + quad * 8;
      {
        bf16x8 bh = *(const bf16x8*)(BsH + nbase);
        bf16x8 bl = *(const bf16x8*)(BsL + nbase);
        acc[jlf][0] = __builtin_amdgcn_mfma_f32_16x16x32_bf16(ah, bh, acc[jlf][0], 0, 0, 0);
        acc[jlf][0] = __builtin_amdgcn_mfma_f32_16x16x32_bf16(al, bh, acc[jlf][0], 0, 0, 0);
        acc[jlf][0] = __builtin_amdgcn_mfma_f32_16x16x32_bf16(ah, bl, acc[jlf][0], 0, 0, 0);
      }
      {
        bf16x8 bh = *(const bf16x8*)(BsH + BJ * BKP + nbase);
        bf16x8 bl = *(const bf16x8*)(BsL + BJ * BKP + nbase);
        acc[jlf][1] = __builtin_amdgcn_mfma_f32_16x16x32_bf16(ah, bh, acc[jlf][1], 0, 0, 0);
        acc[jlf][1] = __builtin_amdgcn_mfma_f32_16x16x32_bf16(al, bh, acc[jlf][1], 0, 0, 0);
        acc[jlf][1] = __builtin_amdgcn_mfma_f32_16x16x32_bf16(ah, bl, acc[jlf][1], 0, 0, 0);
      }
      {
        bf16x8 bh = *(const bf16x8*)(BsH + 2 * BJ * BKP + nbase);
        bf16x8 bl = *(const bf16x8*)(BsL + 2 * BJ * BKP + nbase);
        acc[jlf][G2] = __builtin_amdgcn_mfma_f32_16x16x32_bf16(ah, bh, acc[jlf][G2], 0, 0, 0);
        acc[jlf][G2] = __builtin_amdgcn_mfma_f32_16x16x32_bf16(al, bh, acc[jlf][G2], 0, 0, 0);
        acc[jlf][G2] = __builtin_amdgcn_mfma_f32_16x16x32_bf16(ah, bl, acc[jlf][G2], 0, 0, 0);
      }
    }
    __syncthreads();
  }
}

// acc gates: 0=r(sum), 1=z(sum), 2=nI, 3=nH. Applies GRU, writes hnew (and window slot).
__device__ __forceinline__ void ew_gru(
    f32x4 acc[2][4],
    const float* __restrict__ bi, const float* __restrict__ bh,
    const float* __restrict__ hold, float* __restrict__ hnew,
    int b0, int j0, int tid, __hip_bfloat16* win, int slot)
{
  const int wv = tid >> 6, lane = tid & 63, quad = lane >> 4, l15 = lane & 15;
  const int ms = wv & 1, jh = wv >> 1;
#pragma unroll
  for (int jlf = 0; jlf < 2; ++jlf) {
    const int j = j0 + jh * 32 + jlf * 16 + l15;
    const float br = bi[j] + bh[j];
    const float bz = bi[NH + j] + bh[NH + j];
    const float bni = bi[2 * NH + j];
    const float bnh = bh[2 * NH + j];
#pragma unroll
    for (int rg = 0; rg < 4; ++rg) {
      const int b = b0 + ms * 16 + quad * 4 + rg;
      const float r = sigmoidf_(acc[jlf][0][rg] + br);
      const float z = sigmoidf_(acc[jlf][1][rg] + bz);
      const float n = tanhf_(acc[jlf][2][rg] + bni + r * (acc[jlf][3][rg] + bnh));
      const float h = hold[(size_t)b * NH + j];
      const float hn = (1.f - z) * n + z * h;
      hnew[(size_t)b * NH + j] = hn;
      if (win) win[((size_t)b * NW + slot) * NH + j] = __float2bfloat16(hn);
    }
  }
}

__device__ __forceinline__ void store_ghh1(f32x4 acc[2][4], float* __restrict__ ghh1,
                                           int b0, int j0, int tid)
{
  const int wv = tid >> 6, lane = tid & 63, quad = lane >> 4, l15 = lane & 15;
  const int ms = wv & 1, jh = wv >> 1;
#pragma unroll
  for (int jlf = 0; jlf < 2; ++jlf) {
    const int j = j0 + jh * 32 + jlf * 16 + l15;
#pragma unroll
    for (int rg = 0; rg < 4; ++rg) {
      const int b = b0 + ms * 16 + quad * 4 + rg;
      float* gr = ghh1 + (size_t)b * G3;
      gr[j] = acc[jlf][0][rg];
      gr[NH + j] = acc[jlf][1][rg];
      gr[2 * NH + j] = acc[jlf][2][rg];
    }
  }
}

// decoder layer-1 EW: combine input-proj acc with ghh1 (hidden proj), update h1 in place,
// write window slot (bf16), compute temporal-weighted t-vector.
__device__ __forceinline__ void ew_dec1(
    f32x4 acc[2][4], const Params& P, float* __restrict__ h1p,
    int b0, int j0, int tid, int s)
{
  const int wv = tid >> 6, lane = tid & 63, quad = lane >> 4, l15 = lane & 15;
  const int ms = wv & 1, jh = wv >> 1;
  const int slot = s % NW;
  float twv[NW];
#pragma unroll
  for (int k = 0; k < NW; ++k) {
    int idx = k - slot - 1; if (idx < 0) idx += NW;
    twv[k] = P.tw[idx];
  }
  const float tw9 = P.tw[NW - 1];   // weight of the newest entry (always tw[9])
  const float tb0 = P.tb[0];
#pragma unroll
  for (int jlf = 0; jlf < 2; ++jlf) {
    const int j = j0 + jh * 32 + jlf * 16 + l15;
    const float br = P.bih1[j] + P.bhh1[j];
    const float bz = P.bih1[NH + j] + P.bhh1[NH + j];
    const float bni = P.bih1[2 * NH + j];
    const float bnh = P.bhh1[2 * NH + j];
#pragma unroll
    for (int rg = 0; rg < 4; ++rg) {
      const int b = b0 + ms * 16 + quad * 4 + rg;
      const float* gh = P.ghh1 + (size_t)b * G3;
      const float r = sigmoidf_(acc[jlf][0][rg] + gh[j] + br);
      const float z = sigmoidf_(acc[jlf][1][rg] + gh[NH + j] + bz);
      const float n = tanhf_(acc[jlf][2][rg] + bni + r * (gh[2 * NH + j] + bnh));
      const float h = h1p[(size_t)b * NH + j];
      const float hn = (1.f - z) * n + z * h;
      h1p[(size_t)b * NH + j] = hn;
      __hip_bfloat16* wrow = P.winb + (size_t)b * NW * NH + j;
      wrow[(size_t)slot * NH] = __float2bfloat16(hn);
      float ts = tb0 + hn * tw9;
#pragma unroll
      for (int k = 0; k < NW; ++k) {
        if (k == slot) continue;
        ts += __bfloat162float(wrow[(size_t)k * NH]) * twv[k];
      }
      P.tvec[(size_t)b * NH + j] = ts;
    }
  }
}

template <bool PS>
__global__ __launch_bounds__(NTHR) void rnn_kernel(Params P) {
  __shared__ __align__(16) __hip_bfloat16 AsH[BM * BKP];
  __shared__ __align__(16) __hip_bfloat16 AsL[BM * BKP];
  __shared__ __align__(16) __hip_bfloat16 BsH[3 * BJ * BKP];
  __shared__ __align__(16) __hip_bfloat16 BsL[3 * BJ * BKP];
  __shared__ __align__(16) float tl[2 * NH];
  const int tid = threadIdx.x;
  const int wg = blockIdx.x;
  const size_t gid = (size_t)wg * NTHR + tid;
  const size_t GT = (size_t)NWG * NTHR;
  unsigned gen = 0;

  // ---- init: split Wih0 (padded to CP), optionally big weights; zero states; decin ----
  for (size_t i = gid; i < (size_t)G3 * CP; i += GT) {
    const int row = (int)(i / CP), k = (int)(i - (size_t)row * CP);
    split2(k < NC ? P.Wih0[(size_t)row * NC + k] : 0.f, P.Wih0h[i], P.Wih0l[i]);
  }
  if (PS) {
    for (size_t i = gid; i < (size_t)G3 * NH; i += GT) {
      split2(P.Whh0[i], P.Whh0h[i], P.Whh0l[i]);
      split2(P.Wih1[i], P.Wih1h[i], P.Wih1l[i]);
      split2(P.Whh1[i], P.Whh1h[i], P.Whh1l[i]);
    }
  }
  for (size_t i = gid; i < (size_t)2 * NB * NH; i += GT) { P.h0[i] = 0.f; P.h1[i] = 0.f; }
  for (size_t i = gid; i < (size_t)NB * CP; i += GT) {
    const int b = (int)(i / CP), k = (int)(i - (size_t)b * CP);
    P.decin[i] = (k < NC) ? P.x[((size_t)b * NT + (NT - 1)) * NC + k] : 0.f;
  }
  gbar(P.bar, gen, tid);

  const bool isL1 = wg >= 128;
  const int tile = wg & 127;
  // XCD-aware map: j-group == wg%8 -> each weight slice stays in one XCD's L2
  const int b0 = (tile >> 3) * BM;
  const int j0 = (tile & 7) * BJ;

  // ---- encoder: pipelined layer0/layer1, one grid barrier per iteration ----
  for (int t = 0; t <= NT; ++t) {
    const int cur = t & 1;
    float* h0c = P.h0 + (size_t)cur * NB * NH;
    float* h0n = P.h0 + (size_t)(cur ^ 1) * NB * NH;
    float* h1c = P.h1 + (size_t)cur * NB * NH;
    float* h1n = P.h1 + (size_t)(cur ^ 1) * NB * NH;
    f32x4 acc[2][4];
    if (!isL1) {
      if (t < NT) {
        zacc(acc);
        gemm_tile<2, true>(acc, P.Wih0h, P.Wih0l, nullptr, CP, AM_X, P.x, t, b0, j0, AsH, AsL, BsH, BsL, tid);
        gemm_tile<3, PS>(acc, P.Whh0h, P.Whh0l, P.Whh0, NH, AM_H, h0c, 0, b0, j0, AsH, AsL, BsH, BsL, tid);
        ew_gru(acc, P.bih0, P.bhh0, h0c, h0n, b0, j0, tid, nullptr, 0);
      }
    } else {
      if (t >= 1) {  // layer1 processes time t-1 with input ys0_{t-1} = current h0
        zacc(acc);
        gemm_tile<2, PS>(acc, P.Wih1h, P.Wih1l, P.Wih1, NH, AM_H, h0c, 0, b0, j0, AsH, AsL, BsH, BsL, tid);
        gemm_tile<3, PS>(acc, P.Whh1h, P.Whh1l, P.Whh1, NH, AM_H, h1c, 0, b0, j0, AsH, AsL, BsH, BsL, tid);
        ew_gru(acc, P.bih1, P.bhh1, h1c, h1n, b0, j0, tid,
               (t >= 119) ? P.winb : nullptr, t - 119);
      }
    }
    gbar(P.bar, gen, tid);
  }

  // final states: h0 in buffer 0 (last write t=127), h1 in buffer 1 (last write t=128)
  int d0 = 0;
  float* h1p = P.h1 + (size_t)NB * NH;

  // ---- decoder: 3 grid barriers per step ----
  for (int s = 0; s < NT; ++s) {
    float* h0c = P.h0 + (size_t)d0 * NB * NH;
    float* h0n = P.h0 + (size_t)(d0 ^ 1) * NB * NH;
    f32x4 acc[2][4];
    if (!isL1) {          // gates0 (input=decin) + EW0 -> h0n
      zacc(acc);
      gemm_tile<2, true>(acc, P.Wih0h, P.Wih0l, nullptr, CP, AM_DEC, P.decin, 0, b0, j0, AsH, AsL, BsH, BsL, tid);
      gemm_tile<3, PS>(acc, P.Whh0h, P.Whh0l, P.Whh0, NH, AM_H, h0c, 0, b0, j0, AsH, AsL, BsH, BsL, tid);
      ew_gru(acc, P.bih0, P.bhh0, h0c, h0n, b0, j0, tid, nullptr, 0);
    } else {              // h1 @ Whh1 -> ghh1 (raw, biases added in ew_dec1)
      zacc(acc);
      gemm_tile<2, PS>(acc, P.Whh1h, P.Whh1l, P.Whh1, NH, AM_H, h1p, 0, b0, j0, AsH, AsL, BsH, BsL, tid);
      store_ghh1(acc, P.ghh1, b0, j0, tid);
    }
    gbar(P.bar, gen, tid);
    if (!isL1) {          // gates1 = h0n @ Wih1 (+ghh1) -> EW1, window, t-vector
      zacc(acc);
      gemm_tile<2, PS>(acc, P.Wih1h, P.Wih1l, P.Wih1, NH, AM_H, h0n, 0, b0, j0, AsH, AsL, BsH, BsL, tid);
      ew_dec1(acc, P, h1p, b0, j0, tid, s);
    }
    gbar(P.bar, gen, tid);
    // ---- frame: frame[b,c] = tvec[b,:] @ sw[c,:] + sb[c] + decin[b,c] ----
    {
      for (int i = tid; i < 2 * NH; i += NTHR)
        tl[i] = P.tvec[((size_t)wg * 2 + (i >> 9)) * NH + (i & (NH - 1))];
      __syncthreads();
      if (tid < 2 * NC) {
        const int bl = (tid >= NC) ? 1 : 0;
        const int c = tid - bl * NC;
        const int b = wg * 2 + bl;
        float a = P.sb[c] + P.decin[(size_t)b * CP + c];
        const float4* swr = (const float4*)(P.sw + (size_t)c * NH);
        const float4* tr = (const float4*)(tl + bl * NH);
#pragma unroll 4
        for (int h4 = 0; h4 < NH / 4; ++h4) {
          float4 tv = tr[h4], wv4 = swr[h4];
          a += tv.x * wv4.x + tv.y * wv4.y + tv.z * wv4.z + tv.w * wv4.w;
        }
        P.out[((size_t)b * NT + s) * NC + c] = a;
        P.decin[(size_t)b * CP + c] = a;
      }
      __syncthreads();
    }
    gbar(P.bar, gen, tid);
    d0 ^= 1;
  }
}

extern "C" void kernel_launch(void* const* d_in, const int* in_sizes, int n_in,
                              void* d_out, int out_size, void* d_ws, size_t ws_size,
                              hipStream_t stream) {
  (void)in_sizes; (void)n_in; (void)out_size;
  Params P;
  P.x    = (const float*)d_in[0];
  P.Wih0 = (const float*)d_in[1];
  P.Whh0 = (const float*)d_in[2];
  P.bih0 = (const float*)d_in[3];
  P.bhh0 = (const float*)d_in[4];
  P.Wih1 = (const float*)d_in[5];
  P.Whh1 = (const float*)d_in[6];
  P.bih1 = (const float*)d_in[7];
  P.bhh1 = (const float*)d_in[8];
  P.tw   = (const float*)d_in[9];
  P.tb   = (const float*)d_in[10];
  P.sw   = (const float*)d_in[11];
  P.sb   = (const float*)d_in[12];
  P.out  = (float*)d_out;

  char* w = (char*)d_ws;
  size_t used = 0;
  auto take = [&](size_t bytes) {
    char* p = w + used;
    used += (bytes + 255) & ~(size_t)255;
    return p;
  };
  P.bar   = (unsigned*)take(256);
  P.Wih0h = (__hip_bfloat16*)take((size_t)G3 * CP * 2);
  P.Wih0l = (__hip_bfloat16*)take((size_t)G3 * CP * 2);
  P.h0    = (float*)take((size_t)2 * NB * NH * 4);
  P.h1    = (float*)take((size_t)2 * NB * NH * 4);
  P.decin = (float*)take((size_t)NB * CP * 4);
  P.ghh1  = (float*)take((size_t)NB * G3 * 4);
  P.tvec  = (float*)take((size_t)NB * NH * 4);
  P.winb  = (__hip_bfloat16*)take((size_t)NB * NW * NH * 2);
  // optional pre-split big weights at the tail
  size_t big = (size_t)G3 * NH * 2;
  char* opt = w + used;
  size_t need_full = used + 6 * ((big + 255) & ~(size_t)255);
  bool presplit = ws_size >= need_full;
  P.Whh0h = (__hip_bfloat16*)(opt + 0 * ((big + 255) & ~(size_t)255));
  P.Whh0l = (__hip_bfloat16*)(opt + 1 * ((big + 255) & ~(size_t)255));
  P.Wih1h = (__hip_bfloat16*)(opt + 2 * ((big + 255) & ~(size_t)255));
  P.Wih1l = (__hip_bfloat16*)(opt + 3 * ((big + 255) & ~(size_t)255));
  P.Whh1h = (__hip_bfloat16*)(opt + 4 * ((big + 255) & ~(size_t)255));
  P.Whh1l = (__hip_bfloat16*)(opt + 5 * ((big + 255) & ~(size_t)255));

  hipMemsetAsync(d_ws, 0, 256, stream);   // zero the barrier counter (capturable node)
  if (presplit)
    rnn_kernel<true><<<dim3(NWG), dim3(NTHR), 0, stream>>>(P);
  else
    rnn_kernel<false><<<dim3(NWG), dim3(NTHR), 0, stream>>>(P);
}

// Round 4
// 19411.873 us; speedup vs baseline: 1.3327x; 1.3327x over previous
//
#include <hip/hip_runtime.h>
#include <hip/hip_bf16.h>

typedef __attribute__((ext_vector_type(8))) short bf16x8;
typedef __attribute__((ext_vector_type(4))) float f32x4;

#define NB 512      // batch
#define NT 128      // timesteps
#define NC 66       // input channels
#define NH 512      // hidden
#define NW 10       // window
#define CP 96       // padded C (multiple of 32)
#define BM 32       // batch tile
#define BJ 64       // j (h-dim) tile -> 3 gate chunks of 64 cols each
#define BK 32       // K step (MFMA K=32)
#define BKP 40      // padded LDS row stride (80B = 5*16B)
#define NWG 256
#define NTHR 256
#define G3 1536     // 3*NH

struct Params {
  const float *x, *Wih0, *Whh0, *bih0, *bhh0, *Wih1, *Whh1, *bih1, *bhh1, *tw, *tb, *sw, *sb;
  float *out;
  unsigned *barL, *barG;               // hierarchical barrier counters (memset 0 on stream)
  __hip_bfloat16 *Wih0h, *Wih0l;       // layer0 input weights: always pre-split (K padded to CP)
  __hip_bfloat16 *Whh0h, *Whh0l, *Wih1h, *Wih1l, *Whh1h, *Whh1l;  // only valid if PS
  float *h0, *h1, *decin, *ghh1, *tvec;
  __hip_bfloat16 *winb;                // sliding window, bf16
};

__device__ __forceinline__ float sigmoidf_(float x) { return 1.f / (1.f + __expf(-x)); }
__device__ __forceinline__ float tanhf_(float x) {
  float e = __expf(2.f * x);
  return (e - 1.f) / (e + 1.f);
}
__device__ __forceinline__ void split2(float v, __hip_bfloat16& h, __hip_bfloat16& l) {
  h = __float2bfloat16(v);
  l = __float2bfloat16(v - __bfloat162float(h));
}
__device__ __forceinline__ unsigned short bfbits(__hip_bfloat16 h) { return *(unsigned short*)&h; }
__device__ __forceinline__ void splitpack4(float4 v, ushort4& ph, ushort4& pl) {
  __hip_bfloat16 h, l;
  split2(v.x, h, l); ph.x = bfbits(h); pl.x = bfbits(l);
  split2(v.y, h, l); ph.y = bfbits(h); pl.y = bfbits(l);
  split2(v.z, h, l); ph.z = bfbits(h); pl.z = bfbits(l);
  split2(v.w, h, l); ph.w = bfbits(h); pl.w = bfbits(l);
}

// device-coherent (L1/L2-bypass) reads for cross-XCD activation data.
// agent-scope relaxed atomic load -> global_load ... sc0 sc1 (reads at L3 coherence point).
__device__ __forceinline__ float4 cload4(const float* p) {
  unsigned long long a = __hip_atomic_load((const unsigned long long*)p,       __ATOMIC_RELAXED, __HIP_MEMORY_SCOPE_AGENT);
  unsigned long long b = __hip_atomic_load(((const unsigned long long*)p) + 1, __ATOMIC_RELAXED, __HIP_MEMORY_SCOPE_AGENT);
  float4 r;
  ((unsigned long long*)&r)[0] = a;
  ((unsigned long long*)&r)[1] = b;
  return r;
}
__device__ __forceinline__ float cload1(const float* p) {
  return __hip_atomic_load(p, __ATOMIC_RELAXED, __HIP_MEMORY_SCOPE_AGENT);
}
__device__ __forceinline__ float cloadbf(const __hip_bfloat16* p) {
  unsigned short u = __hip_atomic_load((const unsigned short*)p, __ATOMIC_RELAXED, __HIP_MEMORY_SCOPE_AGENT);
  __hip_bfloat16 h = *(__hip_bfloat16*)&u;
  return __bfloat162float(h);
}

// Hierarchical fence-light grid barrier.
// Arrival: RELEASE fetch_add on per-group counter (emits buffer_wbl2: write-back L2, NO invalidate
// -> weights stay L2-resident). Last arriver of a group bumps the global counter.
// Wait: RELAXED agent-scope poll (sc-bypass load, no buffer_inv).
// Cross-phase data is read via cload* (sc0 sc1) by consumers, so no acquire-invalidate is needed.
__device__ __forceinline__ void gbar(unsigned* barL, unsigned* barG, unsigned& phase,
                                     int tid, int grp) {
  __syncthreads();
  ++phase;
  if (tid == 0) {
    unsigned old = __hip_atomic_fetch_add(&barL[grp * 32], 1u, __ATOMIC_RELEASE,
                                          __HIP_MEMORY_SCOPE_AGENT);
    if (old == phase * 32 - 1)
      __hip_atomic_fetch_add(barG, 1u, __ATOMIC_RELAXED, __HIP_MEMORY_SCOPE_AGENT);
    while (__hip_atomic_load(barG, __ATOMIC_RELAXED, __HIP_MEMORY_SCOPE_AGENT) < phase)
      __builtin_amdgcn_s_sleep(2);
  }
  __syncthreads();
  asm volatile("" ::: "memory");
}

#define AM_X 0
#define AM_DEC 1
#define AM_H 2

__device__ __forceinline__ float4 loadA(int amode, const float* __restrict__ A, int tstep,
                                        int b0, int am, int k) {
  if (amode == AM_X) {            // read-only input: plain cached loads
    const float* xr = A + ((size_t)(b0 + am) * NT + tstep) * NC;
    float4 v;
    v.x = (k + 0 < NC) ? xr[k + 0] : 0.f;
    v.y = (k + 1 < NC) ? xr[k + 1] : 0.f;
    v.z = (k + 2 < NC) ? xr[k + 2] : 0.f;
    v.w = (k + 3 < NC) ? xr[k + 3] : 0.f;
    return v;
  } else if (amode == AM_DEC) {   // cross-WG activation: coherent
    return cload4(A + (size_t)(b0 + am) * CP + k);
  } else {                        // cross-WG activation: coherent
    return cload4(A + (size_t)(b0 + am) * NH + k);
  }
}

__device__ __forceinline__ void zacc(f32x4 acc[2][4]) {
#pragma unroll
  for (int i = 0; i < 2; ++i)
#pragma unroll
    for (int g = 0; g < 4; ++g) {
      acc[i][g][0] = 0.f; acc[i][g][1] = 0.f; acc[i][g][2] = 0.f; acc[i][g][3] = 0.f;
    }
}

// (BM x 3*BJ) tile of gates[b, g*512+j] += A[b,:] @ W[g*512+j, :]^T with split-bf16:
// acc += Ahi*Whi + Alo*Whi + Ahi*Wlo. A-tile prefetched one k-step ahead (coherent-load latency).
template <int G2, bool PSW>
__device__ __forceinline__ void gemm_tile(
    f32x4 acc[2][4],
    const __hip_bfloat16* __restrict__ Wh, const __hip_bfloat16* __restrict__ Wl,
    const float* __restrict__ Wf, int Kb,
    int amode, const float* __restrict__ A, int tstep,
    int b0, int j0,
    __hip_bfloat16* AsH, __hip_bfloat16* AsL,
    __hip_bfloat16* BsH, __hip_bfloat16* BsL, int tid)
{
  const int wv = tid >> 6, lane = tid & 63, quad = lane >> 4, l15 = lane & 15;
  const int ms = wv & 1, jh = wv >> 1;
  const int am = tid >> 3;          // 0..31 (A row)
  const int ak = (tid & 7) << 2;    // 0..28 (A col group of 4)
  const int nk = Kb >> 5;
  float4 av = loadA(amode, A, tstep, b0, am, ak);
  for (int kk = 0; kk < nk; ++kk) {
    const int kb = kk << 5;
    // issue B loads into regs first (L2-warm weights)
    uint4 bh_[3], bl_[3];
#pragma unroll
    for (int r = 0; r < 3; ++r) {
      const int l = tid + r * NTHR;
      const int nl = l >> 2, k8 = (l & 3) << 3;
      const int g = nl >> 6, jl = nl & 63;
      if (PSW) {
        const size_t woff = (size_t)(g * NH + j0 + jl) * Kb + kb + k8;
        bh_[r] = *(const uint4*)(Wh + woff);
        bl_[r] = *(const uint4*)(Wl + woff);
      } else {
        const float* wp = Wf + (size_t)(g * NH + j0 + jl) * Kb + kb + k8;
        float4 w0 = *(const float4*)wp;
        float4 w1 = *(const float4*)(wp + 4);
        ushort4 ph0, pl0, ph1, pl1;
        splitpack4(w0, ph0, pl0);
        splitpack4(w1, ph1, pl1);
        ((ushort4*)&bh_[r])[0] = ph0; ((ushort4*)&bh_[r])[1] = ph1;
        ((ushort4*)&bl_[r])[0] = pl0; ((ushort4*)&bl_[r])[1] = pl1;
      }
    }
    // stage A (prefetched regs) -> LDS
    {
      ushort4 ph, pl;
      splitpack4(av, ph, pl);
      *(ushort4*)(AsH + am * BKP + ak) = ph;
      *(ushort4*)(AsL + am * BKP + ak) = pl;
    }
    // stage B -> LDS
#pragma unroll
    for (int r = 0; r < 3; ++r) {
      const int l = tid + r * NTHR;
      const int nl = l >> 2, k8 = (l & 3) << 3;
      *(uint4*)(BsH + nl * BKP + k8) = bh_[r];
      *(uint4*)(BsL + nl * BKP + k8) = bl_[r];
    }
    __syncthreads();
    if (kk + 1 < nk)  // prefetch next A-tile; latency overlaps MFMA below
      av = loadA(amode, A, tstep, b0, am, kb + 32 + ak);
    bf16x8 ah = *(const bf16x8*)(AsH + (ms * 16 + l15) * BKP + quad * 8);
    bf16x8 al = *(const bf16x8*)(AsL + (ms * 16 + l15) * BKP + quad * 8);
#pragma unroll
    for (int jlf = 0; jlf < 2; ++jlf) {
      const int nbase = (jh * 32 + jlf * 16 + l15) * BKP + quad * 8;
      {
        bf16x8 bh = *(const bf16x8*)(BsH + nbase);
        bf16x8 bl = *(const bf16x8*)(BsL + nbase);
        acc[jlf][0] = __builtin_amdgcn_mfma_f32_16x16x32_bf16(ah, bh, acc[jlf][0], 0, 0, 0);
        acc[jlf][0] = __builtin_amdgcn_mfma_f32_16x16x32_bf16(al, bh, acc[jlf][0], 0, 0, 0);
        acc[jlf][0] = __builtin_amdgcn_mfma_f32_16x16x32_bf16(ah, bl, acc[jlf][0], 0, 0, 0);
      }
      {
        bf16x8 bh = *(const bf16x8*)(BsH + BJ * BKP + nbase);
        bf16x8 bl = *(const bf16x8*)(BsL + BJ * BKP + nbase);
        acc[jlf][1] = __builtin_amdgcn_mfma_f32_16x16x32_bf16(ah, bh, acc[jlf][1], 0, 0, 0);
        acc[jlf][1] = __builtin_amdgcn_mfma_f32_16x16x32_bf16(al, bh, acc[jlf][1], 0, 0, 0);
        acc[jlf][1] = __builtin_amdgcn_mfma_f32_16x16x32_bf16(ah, bl, acc[jlf][1], 0, 0, 0);
      }
      {
        bf16x8 bh = *(const bf16x8*)(BsH + 2 * BJ * BKP + nbase);
        bf16x8 bl = *(const bf16x8*)(BsL + 2 * BJ * BKP + nbase);
        acc[jlf][G2] = __builtin_amdgcn_mfma_f32_16x16x32_bf16(ah, bh, acc[jlf][G2], 0, 0, 0);
        acc[jlf][G2] = __builtin_amdgcn_mfma_f32_16x16x32_bf16(al, bh, acc[jlf][G2], 0, 0, 0);
        acc[jlf][G2] = __builtin_amdgcn_mfma_f32_16x16x32_bf16(ah, bl, acc[jlf][G2], 0, 0, 0);
      }
    }
    __syncthreads();
  }
}

// acc gates: 0=r(sum), 1=z(sum), 2=nI, 3=nH. hold/hnew are same-WG RAW -> plain loads OK.
__device__ __forceinline__ void ew_gru(
    f32x4 acc[2][4],
    const float* __restrict__ bi, const float* __restrict__ bh,
    const float* __restrict__ hold, float* __restrict__ hnew,
    int b0, int j0, int tid, __hip_bfloat16* win, int slot)
{
  const int wv = tid >> 6, lane = tid & 63, quad = lane >> 4, l15 = lane & 15;
  const int ms = wv & 1, jh = wv >> 1;
#pragma unroll
  for (int jlf = 0; jlf < 2; ++jlf) {
    const int j = j0 + jh * 32 + jlf * 16 + l15;
    const float br = bi[j] + bh[j];
    const float bz = bi[NH + j] + bh[NH + j];
    const float bni = bi[2 * NH + j];
    const float bnh = bh[2 * NH + j];
#pragma unroll
    for (int rg = 0; rg < 4; ++rg) {
      const int b = b0 + ms * 16 + quad * 4 + rg;
      const float r = sigmoidf_(acc[jlf][0][rg] + br);
      const float z = sigmoidf_(acc[jlf][1][rg] + bz);
      const float n = tanhf_(acc[jlf][2][rg] + bni + r * (acc[jlf][3][rg] + bnh));
      const float h = hold[(size_t)b * NH + j];
      const float hn = (1.f - z) * n + z * h;
      hnew[(size_t)b * NH + j] = hn;
      if (win) win[((size_t)b * NW + slot) * NH + j] = __float2bfloat16(hn);
    }
  }
}

__device__ __forceinline__ void store_ghh1(f32x4 acc[2][4], float* __restrict__ ghh1,
                                           int b0, int j0, int tid)
{
  const int wv = tid >> 6, lane = tid & 63, quad = lane >> 4, l15 = lane & 15;
  const int ms = wv & 1, jh = wv >> 1;
#pragma unroll
  for (int jlf = 0; jlf < 2; ++jlf) {
    const int j = j0 + jh * 32 + jlf * 16 + l15;
#pragma unroll
    for (int rg = 0; rg < 4; ++rg) {
      const int b = b0 + ms * 16 + quad * 4 + rg;
      float* gr = ghh1 + (size_t)b * G3;
      gr[j] = acc[jlf][0][rg];
      gr[NH + j] = acc[jlf][1][rg];
      gr[2 * NH + j] = acc[jlf][2][rg];
    }
  }
}

// decoder layer-1 EW. ghh1 written by partner L1 WG (cross-CU) -> coherent reads.
// winb slots from prior steps/encoder -> coherent reads. h1p is same-WG -> plain.
__device__ __forceinline__ void ew_dec1(
    f32x4 acc[2][4], const Params& P, float* __restrict__ h1p,
    int b0, int j0, int tid, int s)
{
  const int wv = tid >> 6, lane = tid & 63, quad = lane >> 4, l15 = lane & 15;
  const int ms = wv & 1, jh = wv >> 1;
  const int slot = s % NW;
  float twv[NW];
#pragma unroll
  for (int k = 0; k < NW; ++k) {
    int idx = k - slot - 1; if (idx < 0) idx += NW;
    twv[k] = P.tw[idx];
  }
  const float tw9 = P.tw[NW - 1];
  const float tb0 = P.tb[0];
#pragma unroll
  for (int jlf = 0; jlf < 2; ++jlf) {
    const int j = j0 + jh * 32 + jlf * 16 + l15;
    const float br = P.bih1[j] + P.bhh1[j];
    const float bz = P.bih1[NH + j] + P.bhh1[NH + j];
    const float bni = P.bih1[2 * NH + j];
    const float bnh = P.bhh1[2 * NH + j];
#pragma unroll
    for (int rg = 0; rg < 4; ++rg) {
      const int b = b0 + ms * 16 + quad * 4 + rg;
      const float* gh = P.ghh1 + (size_t)b * G3;
      const float r = sigmoidf_(acc[jlf][0][rg] + cload1(gh + j) + br);
      const float z = sigmoidf_(acc[jlf][1][rg] + cload1(gh + NH + j) + bz);
      const float n = tanhf_(acc[jlf][2][rg] + bni + r * (cload1(gh + 2 * NH + j) + bnh));
      const float h = h1p[(size_t)b * NH + j];
      const float hn = (1.f - z) * n + z * h;
      h1p[(size_t)b * NH + j] = hn;
      __hip_bfloat16* wrow = P.winb + (size_t)b * NW * NH + j;
      wrow[(size_t)slot * NH] = __float2bfloat16(hn);
      float ts = tb0 + hn * tw9;
#pragma unroll
      for (int k = 0; k < NW; ++k) {
        if (k == slot) continue;
        ts += cloadbf(wrow + (size_t)k * NH) * twv[k];
      }
      P.tvec[(size_t)b * NH + j] = ts;
    }
  }
}

template <bool PS>
__global__ __launch_bounds__(NTHR) void rnn_kernel(Params P) {
  __shared__ __align__(16) __hip_bfloat16 AsH[BM * BKP];
  __shared__ __align__(16) __hip_bfloat16 AsL[BM * BKP];
  __shared__ __align__(16) __hip_bfloat16 BsH[3 * BJ * BKP];
  __shared__ __align__(16) __hip_bfloat16 BsL[3 * BJ * BKP];
  __shared__ __align__(16) float tl[2 * NH];
  const int tid = threadIdx.x;
  const int wg = blockIdx.x;
  const int grp = wg & 7;
  const size_t gid = (size_t)wg * NTHR + tid;
  const size_t GT = (size_t)NWG * NTHR;
  unsigned phase = 0;

  // ---- init: split Wih0 (padded to CP), optionally big weights; zero states; decin ----
  for (size_t i = gid; i < (size_t)G3 * CP; i += GT) {
    const int row = (int)(i / CP), k = (int)(i - (size_t)row * CP);
    split2(k < NC ? P.Wih0[(size_t)row * NC + k] : 0.f, P.Wih0h[i], P.Wih0l[i]);
  }
  if (PS) {
    for (size_t i = gid; i < (size_t)G3 * NH; i += GT) {
      split2(P.Whh0[i], P.Whh0h[i], P.Whh0l[i]);
      split2(P.Wih1[i], P.Wih1h[i], P.Wih1l[i]);
      split2(P.Whh1[i], P.Whh1h[i], P.Whh1l[i]);
    }
  }
  for (size_t i = gid; i < (size_t)2 * NB * NH; i += GT) { P.h0[i] = 0.f; P.h1[i] = 0.f; }
  for (size_t i = gid; i < (size_t)NB * CP; i += GT) {
    const int b = (int)(i / CP), k = (int)(i - (size_t)b * CP);
    P.decin[i] = (k < NC) ? P.x[((size_t)b * NT + (NT - 1)) * NC + k] : 0.f;
  }
  gbar(P.barL, P.barG, phase, tid, grp);

  const bool isL1 = wg >= 128;
  const int tile = wg & 127;
  // XCD-aware map: j-group == wg%8 -> each weight slice stays in one XCD's L2
  const int b0 = (tile >> 3) * BM;
  const int j0 = (tile & 7) * BJ;

  // ---- encoder: pipelined layer0/layer1, one grid barrier per iteration ----
  for (int t = 0; t <= NT; ++t) {
    const int cur = t & 1;
    float* h0c = P.h0 + (size_t)cur * NB * NH;
    float* h0n = P.h0 + (size_t)(cur ^ 1) * NB * NH;
    float* h1c = P.h1 + (size_t)cur * NB * NH;
    float* h1n = P.h1 + (size_t)(cur ^ 1) * NB * NH;
    f32x4 acc[2][4];
    if (!isL1) {
      if (t < NT) {
        zacc(acc);
        gemm_tile<2, true>(acc, P.Wih0h, P.Wih0l, nullptr, CP, AM_X, P.x, t, b0, j0, AsH, AsL, BsH, BsL, tid);
        gemm_tile<3, PS>(acc, P.Whh0h, P.Whh0l, P.Whh0, NH, AM_H, h0c, 0, b0, j0, AsH, AsL, BsH, BsL, tid);
        ew_gru(acc, P.bih0, P.bhh0, h0c, h0n, b0, j0, tid, nullptr, 0);
      }
    } else {
      if (t >= 1) {  // layer1 processes time t-1 with input ys0_{t-1} = current h0
        zacc(acc);
        gemm_tile<2, PS>(acc, P.Wih1h, P.Wih1l, P.Wih1, NH, AM_H, h0c, 0, b0, j0, AsH, AsL, BsH, BsL, tid);
        gemm_tile<3, PS>(acc, P.Whh1h, P.Whh1l, P.Whh1, NH, AM_H, h1c, 0, b0, j0, AsH, AsL, BsH, BsL, tid);
        ew_gru(acc, P.bih1, P.bhh1, h1c, h1n, b0, j0, tid,
               (t >= 119) ? P.winb : nullptr, t - 119);
      }
    }
    gbar(P.barL, P.barG, phase, tid, grp);
  }

  // final states: h0 in buffer 0 (last write t=127), h1 in buffer 1 (last write t=128)
  int d0 = 0;
  float* h1p = P.h1 + (size_t)NB * NH;

  // ---- decoder: 3 grid barriers per step ----
  for (int s = 0; s < NT; ++s) {
    float* h0c = P.h0 + (size_t)d0 * NB * NH;
    float* h0n = P.h0 + (size_t)(d0 ^ 1) * NB * NH;
    f32x4 acc[2][4];
    if (!isL1) {          // gates0 (input=decin) + EW0 -> h0n
      zacc(acc);
      gemm_tile<2, true>(acc, P.Wih0h, P.Wih0l, nullptr, CP, AM_DEC, P.decin, 0, b0, j0, AsH, AsL, BsH, BsL, tid);
      gemm_tile<3, PS>(acc, P.Whh0h, P.Whh0l, P.Whh0, NH, AM_H, h0c, 0, b0, j0, AsH, AsL, BsH, BsL, tid);
      ew_gru(acc, P.bih0, P.bhh0, h0c, h0n, b0, j0, tid, nullptr, 0);
    } else {              // h1 @ Whh1 -> ghh1 (raw, biases added in ew_dec1)
      zacc(acc);
      gemm_tile<2, PS>(acc, P.Whh1h, P.Whh1l, P.Whh1, NH, AM_H, h1p, 0, b0, j0, AsH, AsL, BsH, BsL, tid);
      store_ghh1(acc, P.ghh1, b0, j0, tid);
    }
    gbar(P.barL, P.barG, phase, tid, grp);
    if (!isL1) {          // gates1 = h0n @ Wih1 (+ghh1) -> EW1, window, t-vector
      zacc(acc);
      gemm_tile<2, PS>(acc, P.Wih1h, P.Wih1l, P.Wih1, NH, AM_H, h0n, 0, b0, j0, AsH, AsL, BsH, BsL, tid);
      ew_dec1(acc, P, h1p, b0, j0, tid, s);
    }
    gbar(P.barL, P.barG, phase, tid, grp);
    // ---- frame: frame[b,c] = tvec[b,:] @ sw[c,:] + sb[c] + decin[b,c] ----
    {
      // tvec rows 2wg,2wg+1 (1024 floats) staged coherently: written cross-XCD last phase
      *(float4*)&tl[tid * 4] = cload4(P.tvec + (size_t)wg * 2 * NH + tid * 4);
      __syncthreads();
      if (tid < 2 * NC) {
        const int bl = (tid >= NC) ? 1 : 0;
        const int c = tid - bl * NC;
        const int b = wg * 2 + bl;
        float a = P.sb[c] + P.decin[(size_t)b * CP + c];   // decin row: own write last step
        const float4* swr = (const float4*)(P.sw + (size_t)c * NH);
        const float4* tr = (const float4*)(tl + bl * NH);
#pragma unroll 4
        for (int h4 = 0; h4 < NH / 4; ++h4) {
          float4 tv = tr[h4], wv4 = swr[h4];
          a += tv.x * wv4.x + tv.y * wv4.y + tv.z * wv4.z + tv.w * wv4.w;
        }
        P.out[((size_t)b * NT + s) * NC + c] = a;
        P.decin[(size_t)b * CP + c] = a;
      }
      __syncthreads();
    }
    gbar(P.barL, P.barG, phase, tid, grp);
    d0 ^= 1;
  }
}

extern "C" void kernel_launch(void* const* d_in, const int* in_sizes, int n_in,
                              void* d_out, int out_size, void* d_ws, size_t ws_size,
                              hipStream_t stream) {
  (void)in_sizes; (void)n_in; (void)out_size;
  Params P;
  P.x    = (const float*)d_in[0];
  P.Wih0 = (const float*)d_in[1];
  P.Whh0 = (const float*)d_in[2];
  P.bih0 = (const float*)d_in[3];
  P.bhh0 = (const float*)d_in[4];
  P.Wih1 = (const float*)d_in[5];
  P.Whh1 = (const float*)d_in[6];
  P.bih1 = (const float*)d_in[7];
  P.bhh1 = (const float*)d_in[8];
  P.tw   = (const float*)d_in[9];
  P.tb   = (const float*)d_in[10];
  P.sw   = (const float*)d_in[11];
  P.sb   = (const float*)d_in[12];
  P.out  = (float*)d_out;

  char* w = (char*)d_ws;
  size_t used = 0;
  auto take = [&](size_t bytes) {
    char* p = w + used;
    used += (bytes + 255) & ~(size_t)255;
    return p;
  };
  unsigned* bar = (unsigned*)take(2048);      // 8 group lines (128B apart) + global line
  P.barL = bar;                               // index grp*32 -> 128B stride
  P.barG = bar + 8 * 32;
  P.Wih0h = (__hip_bfloat16*)take((size_t)G3 * CP * 2);
  P.Wih0l = (__hip_bfloat16*)take((size_t)G3 * CP * 2);
  P.h0    = (float*)take((size_t)2 * NB * NH * 4);
  P.h1    = (float*)take((size_t)2 * NB * NH * 4);
  P.decin = (float*)take((size_t)NB * CP * 4);
  P.ghh1  = (float*)take((size_t)NB * G3 * 4);
  P.tvec  = (float*)take((size_t)NB * NH * 4);
  P.winb  = (__hip_bfloat16*)take((size_t)NB * NW * NH * 2);
  // optional pre-split big weights at the tail
  size_t big = ((size_t)G3 * NH * 2 + 255) & ~(size_t)255;
  char* opt = w + used;
  bool presplit = ws_size >= used + 6 * big;
  P.Whh0h = (__hip_bfloat16*)(opt + 0 * big);
  P.Whh0l = (__hip_bfloat16*)(opt + 1 * big);
  P.Wih1h = (__hip_bfloat16*)(opt + 2 * big);
  P.Wih1l = (__hip_bfloat16*)(opt + 3 * big);
  P.Whh1h = (__hip_bfloat16*)(opt + 4 * big);
  P.Whh1l = (__hip_bfloat16*)(opt + 5 * big);

  hipMemsetAsync(d_ws, 0, 2048, stream);   // zero barrier counters (capturable node)
  if (presplit)
    rnn_kernel<true><<<dim3(NWG), dim3(NTHR), 0, stream>>>(P);
  else
    rnn_kernel<false><<<dim3(NWG), dim3(NTHR), 0, stream>>>(P);
}

// Round 5
// 15820.708 us; speedup vs baseline: 1.6352x; 1.2270x over previous
//
#include <hip/hip_runtime.h>
#include <hip/hip_bf16.h>

typedef __attribute__((ext_vector_type(8))) short bf16x8;
typedef __attribute__((ext_vector_type(4))) float f32x4;

#define NB 512      // batch
#define NT 128      // timesteps
#define NC 66       // input channels
#define NH 512      // hidden
#define NW 10       // window
#define CP 96       // padded C (multiple of 32)
#define BM 32       // batch tile
#define BJ 64       // j (h-dim) tile -> 3 gate chunks of 64 cols each
#define BK 32       // K step (MFMA K=32)
#define BKP 40      // padded LDS row stride (80B)
#define NWG 256
#define NTHR 256
#define G3 1536     // 3*NH

struct Params {
  const float *x, *Wih0, *Whh0, *bih0, *bhh0, *Wih1, *Whh1, *bih1, *bhh1, *tw, *tb, *sw, *sb;
  float *out;
  unsigned *barL, *barG;
  __hip_bfloat16 *Wih0h, *Wih0l;     // layer0 input weights, pre-split, K padded to CP
  __hip_bfloat16 *Wch, *Wcl;         // composed Wc = Wih0 @ sw  [G3, NH], pre-split
  float *cb;                         // cb = Wih0 @ sb  [G3]
  float *h0, *h1, *tvec;
  __hip_bfloat16 *winb;              // sliding window, bf16, WG-private tiles
};

__device__ __forceinline__ float sigmoidf_(float x) { return 1.f / (1.f + __expf(-x)); }
__device__ __forceinline__ float tanhf_(float x) {
  float e = __expf(2.f * x);
  return (e - 1.f) / (e + 1.f);
}
__device__ __forceinline__ void split2(float v, __hip_bfloat16& h, __hip_bfloat16& l) {
  h = __float2bfloat16(v);
  l = __float2bfloat16(v - __bfloat162float(h));
}
__device__ __forceinline__ unsigned short bfbits(__hip_bfloat16 h) { return *(unsigned short*)&h; }
__device__ __forceinline__ void splitpack4(float4 v, ushort4& ph, ushort4& pl) {
  __hip_bfloat16 h, l;
  split2(v.x, h, l); ph.x = bfbits(h); pl.x = bfbits(l);
  split2(v.y, h, l); ph.y = bfbits(h); pl.y = bfbits(l);
  split2(v.z, h, l); ph.z = bfbits(h); pl.z = bfbits(l);
  split2(v.w, h, l); ph.w = bfbits(h); pl.w = bfbits(l);
}

// device-coherent (L2-bypass) loads for cross-WG activation data
__device__ __forceinline__ float4 cload4(const float* p) {
  unsigned long long a = __hip_atomic_load((const unsigned long long*)p,       __ATOMIC_RELAXED, __HIP_MEMORY_SCOPE_AGENT);
  unsigned long long b = __hip_atomic_load(((const unsigned long long*)p) + 1, __ATOMIC_RELAXED, __HIP_MEMORY_SCOPE_AGENT);
  float4 r;
  ((unsigned long long*)&r)[0] = a;
  ((unsigned long long*)&r)[1] = b;
  return r;
}

// hierarchical fence-light grid barrier (round-4, verified)
__device__ __forceinline__ void gbar(unsigned* barL, unsigned* barG, unsigned& phase,
                                     int tid, int grp) {
  __syncthreads();
  ++phase;
  if (tid == 0) {
    unsigned old = __hip_atomic_fetch_add(&barL[grp * 32], 1u, __ATOMIC_RELEASE,
                                          __HIP_MEMORY_SCOPE_AGENT);
    if (old == phase * 32 - 1)
      __hip_atomic_fetch_add(barG, 1u, __ATOMIC_RELAXED, __HIP_MEMORY_SCOPE_AGENT);
    while (__hip_atomic_load(barG, __ATOMIC_RELAXED, __HIP_MEMORY_SCOPE_AGENT) < phase)
      __builtin_amdgcn_s_sleep(2);
  }
  __syncthreads();
  asm volatile("" ::: "memory");
}

#define AM_X 0
#define AM_H 2

__device__ __forceinline__ float4 loadA(int amode, const float* __restrict__ A, int tstep,
                                        int b0, int am, int k) {
  if (amode == AM_X) {
    const float* xr = A + ((size_t)(b0 + am) * NT + tstep) * NC;
    float4 v;
    v.x = (k + 0 < NC) ? xr[k + 0] : 0.f;
    v.y = (k + 1 < NC) ? xr[k + 1] : 0.f;
    v.z = (k + 2 < NC) ? xr[k + 2] : 0.f;
    v.w = (k + 3 < NC) ? xr[k + 3] : 0.f;
    return v;
  }
  return cload4(A + (size_t)(b0 + am) * NH + k);
}

__device__ __forceinline__ void zacc(f32x4 acc[2][4]) {
#pragma unroll
  for (int i = 0; i < 2; ++i)
#pragma unroll
    for (int g = 0; g < 4; ++g) {
      acc[i][g][0] = 0.f; acc[i][g][1] = 0.f; acc[i][g][2] = 0.f; acc[i][g][3] = 0.f;
    }
}

// (BM x 3*BJ) gate tile, split-bf16 3-term MFMA, double-buffered LDS with
// next-stage loads issued before this stage's MFMA (latency overlap).
template <int G2, bool PSW>
__device__ __forceinline__ void gemm_tile(
    f32x4 acc[2][4],
    const __hip_bfloat16* __restrict__ Wh, const __hip_bfloat16* __restrict__ Wl,
    const float* __restrict__ Wf, int Kb,
    int amode, const float* __restrict__ A, int tstep,
    int b0, int j0,
    __hip_bfloat16* AsH, __hip_bfloat16* AsL,    // [2][BM*BKP]
    __hip_bfloat16* BsH, __hip_bfloat16* BsL,    // [2][3*BJ*BKP]
    int tid)
{
  const int wv = tid >> 6, lane = tid & 63, quad = lane >> 4, l15 = lane & 15;
  const int ms = wv & 1, jh = wv >> 1;
  const int am = tid >> 3;          // 0..31
  const int ak = (tid & 7) << 2;    // 0..28
  const int nk = Kb >> 5;

  uint4 bh_[3], bl_[3];             // PSW staging regs
  float4 w0_[3], w1_[3];            // !PSW staging regs

  auto fetchB = [&](int st) {
    const int kb = st << 5;
#pragma unroll
    for (int r = 0; r < 3; ++r) {
      const int l = tid + r * NTHR;
      const int nl = l >> 2, k8 = (l & 3) << 3;
      const int g = nl >> 6, jl = nl & 63;
      if (PSW) {
        const size_t o = (size_t)(g * NH + j0 + jl) * Kb + kb + k8;
        bh_[r] = *(const uint4*)(Wh + o);
        bl_[r] = *(const uint4*)(Wl + o);
      } else {
        const float* wp = Wf + (size_t)(g * NH + j0 + jl) * Kb + kb + k8;
        w0_[r] = *(const float4*)wp;
        w1_[r] = *(const float4*)(wp + 4);
      }
    }
  };

  float4 av = loadA(amode, A, tstep, b0, am, ak);
  fetchB(0);

  for (int st = 0; st < nk; ++st) {
    const int cur = st & 1;
    __hip_bfloat16* ah_d = AsH + cur * (BM * BKP);
    __hip_bfloat16* al_d = AsL + cur * (BM * BKP);
    __hip_bfloat16* bh_d = BsH + cur * (3 * BJ * BKP);
    __hip_bfloat16* bl_d = BsL + cur * (3 * BJ * BKP);
    // stage st: regs -> LDS
    {
      ushort4 ph, pl;
      splitpack4(av, ph, pl);
      *(ushort4*)(ah_d + am * BKP + ak) = ph;
      *(ushort4*)(al_d + am * BKP + ak) = pl;
    }
#pragma unroll
    for (int r = 0; r < 3; ++r) {
      const int l = tid + r * NTHR;
      const int nl = l >> 2, k8 = (l & 3) << 3;
      if (PSW) {
        *(uint4*)(bh_d + nl * BKP + k8) = bh_[r];
        *(uint4*)(bl_d + nl * BKP + k8) = bl_[r];
      } else {
        ushort4 ph0, pl0, ph1, pl1;
        splitpack4(w0_[r], ph0, pl0);
        splitpack4(w1_[r], ph1, pl1);
        *(ushort4*)(bh_d + nl * BKP + k8) = ph0;
        *(ushort4*)(bh_d + nl * BKP + k8 + 4) = ph1;
        *(ushort4*)(bl_d + nl * BKP + k8) = pl0;
        *(ushort4*)(bl_d + nl * BKP + k8 + 4) = pl1;
      }
    }
    // issue next-stage loads now; latency overlaps sync + MFMA below
    if (st + 1 < nk) {
      av = loadA(amode, A, tstep, b0, am, ((st + 1) << 5) + ak);
      fetchB(st + 1);
    }
    __syncthreads();
    bf16x8 ah = *(const bf16x8*)(ah_d + (ms * 16 + l15) * BKP + quad * 8);
    bf16x8 al = *(const bf16x8*)(al_d + (ms * 16 + l15) * BKP + quad * 8);
#pragma unroll
    for (int jlf = 0; jlf < 2; ++jlf) {
      const int nbase = (jh * 32 + jlf * 16 + l15) * BKP + quad * 8;
      {
        bf16x8 bh = *(const bf16x8*)(bh_d + nbase);
        bf16x8 bl = *(const bf16x8*)(bl_d + nbase);
        acc[jlf][0] = __builtin_amdgcn_mfma_f32_16x16x32_bf16(ah, bh, acc[jlf][0], 0, 0, 0);
        acc[jlf][0] = __builtin_amdgcn_mfma_f32_16x16x32_bf16(al, bh, acc[jlf][0], 0, 0, 0);
        acc[jlf][0] = __builtin_amdgcn_mfma_f32_16x16x32_bf16(ah, bl, acc[jlf][0], 0, 0, 0);
      }
      {
        bf16x8 bh = *(const bf16x8*)(bh_d + BJ * BKP + nbase);
        bf16x8 bl = *(const bf16x8*)(bl_d + BJ * BKP + nbase);
        acc[jlf][1] = __builtin_amdgcn_mfma_f32_16x16x32_bf16(ah, bh, acc[jlf][1], 0, 0, 0);
        acc[jlf][1] = __builtin_amdgcn_mfma_f32_16x16x32_bf16(al, bh, acc[jlf][1], 0, 0, 0);
        acc[jlf][1] = __builtin_amdgcn_mfma_f32_16x16x32_bf16(ah, bl, acc[jlf][1], 0, 0, 0);
      }
      {
        bf16x8 bh = *(const bf16x8*)(bh_d + 2 * BJ * BKP + nbase);
        bf16x8 bl = *(const bf16x8*)(bl_d + 2 * BJ * BKP + nbase);
        acc[jlf][G2] = __builtin_amdgcn_mfma_f32_16x16x32_bf16(ah, bh, acc[jlf][G2], 0, 0, 0);
        acc[jlf][G2] = __builtin_amdgcn_mfma_f32_16x16x32_bf16(al, bh, acc[jlf][G2], 0, 0, 0);
        acc[jlf][G2] = __builtin_amdgcn_mfma_f32_16x16x32_bf16(ah, bl, acc[jlf][G2], 0, 0, 0);
      }
    }
  }
  __syncthreads();   // protect last-read buffer before caller's next gemm reuses it
}

// GRU elementwise; hold/hnew/win tiles are WG-private -> plain loads/stores.
__device__ __forceinline__ void ew_gru(
    f32x4 acc[2][4],
    const float* __restrict__ bi, const float* __restrict__ bh,
    const float* __restrict__ hold, float* __restrict__ hnew,
    int b0, int j0, int tid, __hip_bfloat16* win, int slot)
{
  const int wv = tid >> 6, lane = tid & 63, quad = lane >> 4, l15 = lane & 15;
  const int ms = wv & 1, jh = wv >> 1;
#pragma unroll
  for (int jlf = 0; jlf < 2; ++jlf) {
    const int j = j0 + jh * 32 + jlf * 16 + l15;
    const float br = bi[j] + bh[j];
    const float bz = bi[NH + j] + bh[NH + j];
    const float bni = bi[2 * NH + j];
    const float bnh = bh[2 * NH + j];
#pragma unroll
    for (int rg = 0; rg < 4; ++rg) {
      const int b = b0 + ms * 16 + quad * 4 + rg;
      const float r = sigmoidf_(acc[jlf][0][rg] + br);
      const float z = sigmoidf_(acc[jlf][1][rg] + bz);
      const float n = tanhf_(acc[jlf][2][rg] + bni + r * (acc[jlf][3][rg] + bnh));
      const float h = hold[(size_t)b * NH + j];
      const float hn = (1.f - z) * n + z * h;
      hnew[(size_t)b * NH + j] = hn;
      if (win) win[((size_t)b * NW + slot) * NH + j] = __float2bfloat16(hn);
    }
  }
}

// decoder layer-1 EW: acc already holds input-proj + hidden-proj sums
// (r,z in acc[0],[1]; nI in acc[2]; nH in acc[3]). h1/window/tvec tiles private.
__device__ __forceinline__ void ew_dec1(
    f32x4 acc[2][4], const Params& P, float* __restrict__ h1p,
    int b0, int j0, int tid, int s)
{
  const int wv = tid >> 6, lane = tid & 63, quad = lane >> 4, l15 = lane & 15;
  const int ms = wv & 1, jh = wv >> 1;
  const int slot = s % NW;
  float twv[NW];
#pragma unroll
  for (int k = 0; k < NW; ++k) {
    int idx = k - slot - 1; if (idx < 0) idx += NW;
    twv[k] = P.tw[idx];
  }
  const float tw9 = P.tw[NW - 1];
  const float tb0 = P.tb[0];
#pragma unroll
  for (int jlf = 0; jlf < 2; ++jlf) {
    const int j = j0 + jh * 32 + jlf * 16 + l15;
    const float br = P.bih1[j] + P.bhh1[j];
    const float bz = P.bih1[NH + j] + P.bhh1[NH + j];
    const float bni = P.bih1[2 * NH + j];
    const float bnh = P.bhh1[2 * NH + j];
#pragma unroll
    for (int rg = 0; rg < 4; ++rg) {
      const int b = b0 + ms * 16 + quad * 4 + rg;
      const float r = sigmoidf_(acc[jlf][0][rg] + br);
      const float z = sigmoidf_(acc[jlf][1][rg] + bz);
      const float n = tanhf_(acc[jlf][2][rg] + bni + r * (acc[jlf][3][rg] + bnh));
      const float h = h1p[(size_t)b * NH + j];
      const float hn = (1.f - z) * n + z * h;
      h1p[(size_t)b * NH + j] = hn;
      __hip_bfloat16* wrow = P.winb + (size_t)b * NW * NH + j;
      wrow[(size_t)slot * NH] = __float2bfloat16(hn);
      float ts = tb0 + hn * tw9;
#pragma unroll
      for (int k = 0; k < NW; ++k) {
        if (k == slot) continue;
        ts += __bfloat162float(wrow[(size_t)k * NH]) * twv[k];
      }
      P.tvec[(size_t)b * NH + j] = ts;
    }
  }
}

__global__ __launch_bounds__(NTHR) void rnn_kernel(Params P) {
  __shared__ __align__(16) __hip_bfloat16 AsH[2 * BM * BKP];
  __shared__ __align__(16) __hip_bfloat16 AsL[2 * BM * BKP];
  __shared__ __align__(16) __hip_bfloat16 BsH[2 * 3 * BJ * BKP];
  __shared__ __align__(16) __hip_bfloat16 BsL[2 * 3 * BJ * BKP];
  __shared__ __align__(16) float tl[4 * NH];
  const int tid = threadIdx.x;
  const int wg = blockIdx.x;
  const int grp = wg & 7;
  const size_t gid = (size_t)wg * NTHR + tid;
  const size_t GT = (size_t)NWG * NTHR;
  unsigned phase = 0;
  const int wv = tid >> 6, lane = tid & 63, l15 = lane & 15;
  const int jh = wv >> 1;

  // ---- init ----
  for (size_t i = gid; i < (size_t)G3 * CP; i += GT) {
    const int row = (int)(i / CP), k = (int)(i - (size_t)row * CP);
    split2(k < NC ? P.Wih0[(size_t)row * NC + k] : 0.f, P.Wih0h[i], P.Wih0l[i]);
  }
  // Wc = Wih0 @ sw (fp32 compose, split-bf16 store)
  for (size_t i = gid; i < (size_t)G3 * NH; i += GT) {
    const int r = (int)(i >> 9), h = (int)(i & (NH - 1));
    float a = 0.f;
    for (int c = 0; c < NC; ++c) a += P.Wih0[(size_t)r * NC + c] * P.sw[(size_t)c * NH + h];
    split2(a, P.Wch[i], P.Wcl[i]);
  }
  // cb = Wih0 @ sb
  for (size_t i = gid; i < (size_t)G3; i += GT) {
    float a = 0.f;
    for (int c = 0; c < NC; ++c) a += P.Wih0[i * NC + c] * P.sb[c];
    P.cb[i] = a;
  }
  for (size_t i = gid; i < (size_t)2 * NB * NH; i += GT) { P.h0[i] = 0.f; P.h1[i] = 0.f; }
  gbar(P.barL, P.barG, phase, tid, grp);

  const bool isL1 = wg >= 128;
  const int tile = wg & 127;
  const int b0 = (tile >> 3) * BM;
  const int j0 = (tile & 7) * BJ;

  float G[2][3][4];   // running input-projection gates (decoder), filled at encoder tail

  // ---- encoder: pipelined L0/L1, one barrier per iteration; t==128: G init ----
  for (int t = 0; t <= NT; ++t) {
    const int cur = t & 1;
    float* h0c = P.h0 + (size_t)cur * NB * NH;
    float* h0n = P.h0 + (size_t)(cur ^ 1) * NB * NH;
    float* h1c = P.h1 + (size_t)cur * NB * NH;
    float* h1n = P.h1 + (size_t)(cur ^ 1) * NB * NH;
    f32x4 acc[2][4];
    if (!isL1) {
      if (t < NT) {
        zacc(acc);
        gemm_tile<2, true>(acc, P.Wih0h, P.Wih0l, nullptr, CP, AM_X, P.x, t, b0, j0, AsH, AsL, BsH, BsL, tid);
        gemm_tile<3, false>(acc, nullptr, nullptr, P.Whh0, NH, AM_H, h0c, 0, b0, j0, AsH, AsL, BsH, BsL, tid);
        ew_gru(acc, P.bih0, P.bhh0, h0c, h0n, b0, j0, tid, nullptr, 0);
      } else {
        // G_0 = x[:,127,:] @ Wih0^T
        zacc(acc);
        gemm_tile<2, true>(acc, P.Wih0h, P.Wih0l, nullptr, CP, AM_X, P.x, NT - 1, b0, j0, AsH, AsL, BsH, BsL, tid);
#pragma unroll
        for (int jlf = 0; jlf < 2; ++jlf)
#pragma unroll
          for (int c = 0; c < 3; ++c)
#pragma unroll
            for (int rg = 0; rg < 4; ++rg) G[jlf][c][rg] = acc[jlf][c][rg];
      }
    } else {
      if (t >= 1) {
        zacc(acc);
        gemm_tile<2, false>(acc, nullptr, nullptr, P.Wih1, NH, AM_H, h0c, 0, b0, j0, AsH, AsL, BsH, BsL, tid);
        gemm_tile<3, false>(acc, nullptr, nullptr, P.Whh1, NH, AM_H, h1c, 0, b0, j0, AsH, AsL, BsH, BsL, tid);
        ew_gru(acc, P.bih1, P.bhh1, h1c, h1n, b0, j0, tid,
               (t >= 119) ? P.winb : nullptr, t - 119);
      }
    }
    gbar(P.barL, P.barG, phase, tid, grp);
  }

  int d0 = 0;
  float* h1p = P.h1 + (size_t)NB * NH;

  // decoder-only per-thread state
  float cbr[2][3];
  float Freg[2];
  if (!isL1) {
#pragma unroll
    for (int jlf = 0; jlf < 2; ++jlf)
#pragma unroll
      for (int c = 0; c < 3; ++c)
        cbr[jlf][c] = P.cb[c * NH + j0 + jh * 32 + jlf * 16 + l15];
#pragma unroll
    for (int v = 0; v < 2; ++v) {
      const int t2 = tid + v * NTHR;
      if (t2 < 4 * NC) {
        const int bl = t2 / NC, c = t2 - bl * NC, b = wg * 4 + bl;
        Freg[v] = P.x[((size_t)b * NT + (NT - 1)) * NC + c];
      }
    }
  }

  auto frame_out = [&](int sout) {   // F += tvec_sout @ sw^T + sb; write out[:, sout, :]
    const float* tvb = P.tvec + (size_t)wg * 4 * NH;
    *(float4*)&tl[tid * 8] = cload4(tvb + tid * 8);
    *(float4*)&tl[tid * 8 + 4] = cload4(tvb + tid * 8 + 4);
    __syncthreads();
#pragma unroll
    for (int v = 0; v < 2; ++v) {
      const int t2 = tid + v * NTHR;
      if (t2 < 4 * NC) {
        const int bl = t2 / NC, c = t2 - bl * NC, b = wg * 4 + bl;
        float f = Freg[v] + P.sb[c];
        const float4* swr = (const float4*)(P.sw + (size_t)c * NH);
        const float4* tr = (const float4*)(tl + bl * NH);
#pragma unroll 8
        for (int h4 = 0; h4 < NH / 4; ++h4) {
          float4 tv = tr[h4], wv4 = swr[h4];
          f += tv.x * wv4.x + tv.y * wv4.y + tv.z * wv4.z + tv.w * wv4.w;
        }
        Freg[v] = f;
        P.out[((size_t)b * NT + sout) * NC + c] = f;
      }
    }
    __syncthreads();
  };

  // ---- decoder: 2 barriers per step ----
  for (int s = 0; s < NT; ++s) {
    float* h0c = P.h0 + (size_t)d0 * NB * NH;
    float* h0n = P.h0 + (size_t)(d0 ^ 1) * NB * NH;
    f32x4 acc[2][4];
    if (!isL1) {
      if (s >= 1) frame_out(s - 1);          // pipelined frame output (uses tvec_{s-1})
      zacc(acc);
      if (s >= 1)
        gemm_tile<2, true>(acc, P.Wch, P.Wcl, nullptr, NH, AM_H, P.tvec, 0, b0, j0, AsH, AsL, BsH, BsL, tid);
#pragma unroll
      for (int jlf = 0; jlf < 2; ++jlf)
#pragma unroll
        for (int c = 0; c < 3; ++c)
#pragma unroll
          for (int rg = 0; rg < 4; ++rg) {
            float g = G[jlf][c][rg] + acc[jlf][c][rg] + (s >= 1 ? cbr[jlf][c] : 0.f);
            G[jlf][c][rg] = g;
            acc[jlf][c][rg] = g;             // acc[.][3] stays 0 for Whh0's nH
          }
      gemm_tile<3, false>(acc, nullptr, nullptr, P.Whh0, NH, AM_H, h0c, 0, b0, j0, AsH, AsL, BsH, BsL, tid);
      ew_gru(acc, P.bih0, P.bhh0, h0c, h0n, b0, j0, tid, nullptr, 0);
    } else {
      zacc(acc);
      gemm_tile<3, false>(acc, nullptr, nullptr, P.Whh1, NH, AM_H, h1p, 0, b0, j0, AsH, AsL, BsH, BsL, tid);
    }
    gbar(P.barL, P.barG, phase, tid, grp);
    if (isL1) {
      gemm_tile<2, false>(acc, nullptr, nullptr, P.Wih1, NH, AM_H, h0n, 0, b0, j0, AsH, AsL, BsH, BsL, tid);
      ew_dec1(acc, P, h1p, b0, j0, tid, s);
    }
    gbar(P.barL, P.barG, phase, tid, grp);
    d0 ^= 1;
  }
  if (!isL1) frame_out(NT - 1);   // tail: frame for s=127
}

extern "C" void kernel_launch(void* const* d_in, const int* in_sizes, int n_in,
                              void* d_out, int out_size, void* d_ws, size_t ws_size,
                              hipStream_t stream) {
  (void)in_sizes; (void)n_in; (void)out_size; (void)ws_size;
  Params P;
  P.x    = (const float*)d_in[0];
  P.Wih0 = (const float*)d_in[1];
  P.Whh0 = (const float*)d_in[2];
  P.bih0 = (const float*)d_in[3];
  P.bhh0 = (const float*)d_in[4];
  P.Wih1 = (const float*)d_in[5];
  P.Whh1 = (const float*)d_in[6];
  P.bih1 = (const float*)d_in[7];
  P.bhh1 = (const float*)d_in[8];
  P.tw   = (const float*)d_in[9];
  P.tb   = (const float*)d_in[10];
  P.sw   = (const float*)d_in[11];
  P.sb   = (const float*)d_in[12];
  P.out  = (float*)d_out;

  char* w = (char*)d_ws;
  size_t used = 0;
  auto take = [&](size_t bytes) {
    char* p = w + used;
    used += (bytes + 255) & ~(size_t)255;
    return p;
  };
  unsigned* bar = (unsigned*)take(2048);
  P.barL = bar;
  P.barG = bar + 8 * 32;
  P.Wih0h = (__hip_bfloat16*)take((size_t)G3 * CP * 2);
  P.Wih0l = (__hip_bfloat16*)take((size_t)G3 * CP * 2);
  P.Wch   = (__hip_bfloat16*)take((size_t)G3 * NH * 2);
  P.Wcl   = (__hip_bfloat16*)take((size_t)G3 * NH * 2);
  P.cb    = (float*)take((size_t)G3 * 4);
  P.h0    = (float*)take((size_t)2 * NB * NH * 4);
  P.h1    = (float*)take((size_t)2 * NB * NH * 4);
  P.tvec  = (float*)take((size_t)NB * NH * 4);
  P.winb  = (__hip_bfloat16*)take((size_t)NB * NW * NH * 2);

  hipMemsetAsync(d_ws, 0, 2048, stream);
  rnn_kernel<<<dim3(NWG), dim3(NTHR), 0, stream>>>(P);
}